// Round 1
// baseline (1435.347 us; speedup 1.0000x reference)
//
#include <hip/hip_runtime.h>
#include <math.h>

#define IN_C 64
#define HID_C 128
#define OUT_C 64

// -------- aggregation: one wave per edge, lane = channel --------
__global__ void k_scatter1(const float* __restrict__ x, const int* __restrict__ src,
                           const int* __restrict__ dst, float* __restrict__ agg,
                           float* __restrict__ deg, int E) {
  int gid = blockIdx.x * blockDim.x + threadIdx.x;
  int lane = threadIdx.x & 63;
  int wave = gid >> 6;
  int nwaves = (gridDim.x * blockDim.x) >> 6;
  for (int e = wave; e < E; e += nwaves) {
    int s = src[e];
    int d = dst[e];
    float v = x[s * IN_C + lane];
    atomicAdd(&agg[d * IN_C + lane], v);
    if (lane == 0) atomicAdd(&deg[d], 1.0f);
  }
}

__global__ void k_scatter2(const float* __restrict__ h, const int* __restrict__ src,
                           const int* __restrict__ dst, float* __restrict__ agg, int E) {
  int gid = blockIdx.x * blockDim.x + threadIdx.x;
  int lane = threadIdx.x & 63;
  int wave = gid >> 6;
  int nwaves = (gridDim.x * blockDim.x) >> 6;
  for (int e = wave; e < E; e += nwaves) {
    int s = src[e];
    int d = dst[e];
    float v0 = h[s * HID_C + lane];
    float v1 = h[s * HID_C + 64 + lane];
    atomicAdd(&agg[d * HID_C + lane], v0);
    atomicAdd(&agg[d * HID_C + 64 + lane], v1);
  }
}

// -------- layer 1 linear: h = relu(agg/deg @ W1l^T + x @ W1r^T + b1) --------
// 256 thr: o = t&127, half = t>>7. Weights hoisted to 128 VGPRs/thread.
__global__ __launch_bounds__(256) void k_linear1(
    const float* __restrict__ agg, const float* __restrict__ x,
    const float* __restrict__ Wl, const float* __restrict__ Wr,
    const float* __restrict__ b, const float* __restrict__ deg,
    float* __restrict__ h, int N) {
  constexpr int NPB = 16;
  constexpr int WROW = 68;  // 68*4=272B, 16B-aligned rows, spreads b128 banks
  __shared__ __align__(16) float sWl[HID_C * WROW];
  __shared__ __align__(16) float sWr[HID_C * WROW];
  __shared__ float sb[HID_C];
  __shared__ __align__(16) float sfa[NPB][IN_C];
  __shared__ __align__(16) float sfx[NPB][IN_C];
  int t = threadIdx.x;
  for (int idx = t; idx < HID_C * IN_C; idx += 256) {
    int o = idx >> 6, c = idx & 63;
    sWl[o * WROW + c] = Wl[idx];
    sWr[o * WROW + c] = Wr[idx];
  }
  if (t < HID_C) sb[t] = b[t];
  int base = blockIdx.x * NPB;
  for (int idx = t; idx < NPB * IN_C; idx += 256) {
    int n = idx >> 6, c = idx & 63;
    int i = base + n;
    float a = 0.f, xv = 0.f;
    if (i < N) {
      float inv = 1.0f / fmaxf(deg[i], 1.0f);
      a = agg[i * IN_C + c] * inv;
      xv = x[i * IN_C + c];
    }
    sfa[n][c] = a;
    sfx[n][c] = xv;
  }
  __syncthreads();
  int o = t & 127;
  int half = t >> 7;
  float4 wl[16], wr[16];
  const float4* pl = (const float4*)(sWl + o * WROW);
  const float4* pr = (const float4*)(sWr + o * WROW);
#pragma unroll
  for (int k = 0; k < 16; ++k) { wl[k] = pl[k]; wr[k] = pr[k]; }
  float bo = sb[o];
  for (int n = half; n < NPB; n += 2) {
    int i = base + n;
    if (i >= N) break;
    const float4* fa = (const float4*)(&sfa[n][0]);
    const float4* fx = (const float4*)(&sfx[n][0]);
    float acc = bo;
#pragma unroll
    for (int k = 0; k < 16; ++k) {
      float4 a4 = fa[k], x4 = fx[k];
      acc = fmaf(a4.x, wl[k].x, acc);
      acc = fmaf(a4.y, wl[k].y, acc);
      acc = fmaf(a4.z, wl[k].z, acc);
      acc = fmaf(a4.w, wl[k].w, acc);
      acc = fmaf(x4.x, wr[k].x, acc);
      acc = fmaf(x4.y, wr[k].y, acc);
      acc = fmaf(x4.z, wr[k].z, acc);
      acc = fmaf(x4.w, wr[k].w, acc);
    }
    h[i * HID_C + o] = fmaxf(acc, 0.f);
  }
}

// -------- layer 2 linear: out = sigmoid(agg2/deg @ W2l^T + h @ W2r^T + b2) ----
// 256 thr: o = t&63, chalf = (t>>6)&1 (c-range split), npar = t>>7 (node parity).
// Each thread holds 64-c weight slice in 128 VGPRs; halves reduced through LDS.
__global__ __launch_bounds__(256) void k_linear2(
    const float* __restrict__ agg, const float* __restrict__ h,
    const float* __restrict__ Wl, const float* __restrict__ Wr,
    const float* __restrict__ b, const float* __restrict__ deg,
    float* __restrict__ out, int N) {
  constexpr int NPB = 8;
  constexpr int WROW = 132;  // 132*4=528B rows, 16B-aligned
  __shared__ __align__(16) float sWl[OUT_C * WROW];
  __shared__ __align__(16) float sWr[OUT_C * WROW];
  __shared__ float sb[OUT_C];
  __shared__ __align__(16) float sfa[NPB][HID_C];
  __shared__ __align__(16) float sfh[NPB][HID_C];
  __shared__ float sacc[NPB][OUT_C];
  int t = threadIdx.x;
  for (int idx = t; idx < OUT_C * HID_C; idx += 256) {
    int o = idx >> 7, c = idx & 127;
    sWl[o * WROW + c] = Wl[idx];
    sWr[o * WROW + c] = Wr[idx];
  }
  if (t < OUT_C) sb[t] = b[t];
  int base = blockIdx.x * NPB;
  for (int idx = t; idx < NPB * HID_C; idx += 256) {
    int n = idx >> 7, c = idx & 127;
    int i = base + n;
    float a = 0.f, hv = 0.f;
    if (i < N) {
      float inv = 1.0f / fmaxf(deg[i], 1.0f);
      a = agg[i * HID_C + c] * inv;
      hv = h[i * HID_C + c];
    }
    sfa[n][c] = a;
    sfh[n][c] = hv;
  }
  __syncthreads();
  int o = t & 63;
  int chalf = (t >> 6) & 1;
  int npar = t >> 7;
  float4 wl[16], wr[16];
  const float4* pl = (const float4*)(sWl + o * WROW + chalf * 64);
  const float4* pr = (const float4*)(sWr + o * WROW + chalf * 64);
#pragma unroll
  for (int k = 0; k < 16; ++k) { wl[k] = pl[k]; wr[k] = pr[k]; }
  float part[NPB / 2];
#pragma unroll
  for (int ni = 0; ni < NPB / 2; ++ni) {
    int n = npar + 2 * ni;
    const float4* fa = (const float4*)(&sfa[n][chalf * 64]);
    const float4* fh = (const float4*)(&sfh[n][chalf * 64]);
    float acc = 0.f;
#pragma unroll
    for (int k = 0; k < 16; ++k) {
      float4 a4 = fa[k], h4 = fh[k];
      acc = fmaf(a4.x, wl[k].x, acc);
      acc = fmaf(a4.y, wl[k].y, acc);
      acc = fmaf(a4.z, wl[k].z, acc);
      acc = fmaf(a4.w, wl[k].w, acc);
      acc = fmaf(h4.x, wr[k].x, acc);
      acc = fmaf(h4.y, wr[k].y, acc);
      acc = fmaf(h4.z, wr[k].z, acc);
      acc = fmaf(h4.w, wr[k].w, acc);
    }
    part[ni] = acc;
  }
  if (chalf == 0) {
#pragma unroll
    for (int ni = 0; ni < NPB / 2; ++ni) sacc[npar + 2 * ni][o] = part[ni];
  }
  __syncthreads();
  if (chalf == 1) {
#pragma unroll
    for (int ni = 0; ni < NPB / 2; ++ni) {
      int n = npar + 2 * ni;
      int i = base + n;
      if (i < N) {
        float v = sacc[n][o] + part[ni] + sb[o];
        out[i * OUT_C + o] = 1.0f / (1.0f + __expf(-v));
      }
    }
  }
}

extern "C" void kernel_launch(void* const* d_in, const int* in_sizes, int n_in,
                              void* d_out, int out_size, void* d_ws, size_t ws_size,
                              hipStream_t stream) {
  const float* x   = (const float*)d_in[0];
  const int*   ei  = (const int*)d_in[1];
  const float* W1l = (const float*)d_in[2];
  const float* W1r = (const float*)d_in[3];
  const float* b1  = (const float*)d_in[4];
  const float* W2l = (const float*)d_in[5];
  const float* W2r = (const float*)d_in[6];
  const float* b2  = (const float*)d_in[7];
  float* out = (float*)d_out;

  int N = in_sizes[0] / IN_C;
  int E = in_sizes[1] / 2;
  const int* src = ei;
  const int* dst = ei + E;

  // workspace layout: [deg N f32][agg region N*128 f32 (agg1 & agg2 share)][h N*128 f32]
  char* ws = (char*)d_ws;
  size_t agg_off = (((size_t)N * 4 + 511) / 512) * 512;
  size_t h_off = agg_off + (size_t)N * HID_C * 4;
  float* deg    = (float*)ws;
  float* aggbuf = (float*)(ws + agg_off);
  float* hbuf   = (float*)(ws + h_off);

  // zero deg + agg1 (layer-1 region)
  hipMemsetAsync(ws, 0, agg_off + (size_t)N * IN_C * 4, stream);
  k_scatter1<<<4096, 256, 0, stream>>>(x, src, dst, aggbuf, deg, E);
  k_linear1<<<(N + 15) / 16, 256, 0, stream>>>(aggbuf, x, W1l, W1r, b1, deg, hbuf, N);
  // zero agg2
  hipMemsetAsync(ws + agg_off, 0, (size_t)N * HID_C * 4, stream);
  k_scatter2<<<4096, 256, 0, stream>>>(hbuf, src, dst, aggbuf, E);
  k_linear2<<<(N + 7) / 8, 256, 0, stream>>>(aggbuf, hbuf, W2l, W2r, b2, deg, out, N);
}

// Round 2
// 747.070 us; speedup vs baseline: 1.9213x; 1.9213x over previous
//
#include <hip/hip_runtime.h>
#include <math.h>

#define IN_C 64
#define HID_C 128
#define OUT_C 64

// ============ CSR build (runs every call; graph-capture safe) ============
__global__ void k_hist(const int* __restrict__ dst, int* __restrict__ cnt, int E) {
  int i = blockIdx.x * blockDim.x + threadIdx.x;
  int stride = gridDim.x * blockDim.x;
  for (int e = i; e < E; e += stride) atomicAdd(&cnt[dst[e]], 1);
}

// per-1024-chunk sums
__global__ __launch_bounds__(256) void k_blocksum(const int* __restrict__ cnt,
                                                  int* __restrict__ partial, int N) {
  __shared__ int red[256];
  int b = blockIdx.x, t = threadIdx.x;
  int base = b * 1024 + t * 4;
  int s = 0;
#pragma unroll
  for (int k = 0; k < 4; ++k) { int i = base + k; if (i < N) s += cnt[i]; }
  red[t] = s;
  __syncthreads();
  for (int off = 128; off > 0; off >>= 1) {
    if (t < off) red[t] += red[t + off];
    __syncthreads();
  }
  if (t == 0) partial[b] = red[0];
}

// exclusive scan of <=128 partials, single block
__global__ __launch_bounds__(128) void k_scanpart(int* __restrict__ partial, int nb) {
  __shared__ int s[128];
  int t = threadIdx.x;
  int v = (t < nb) ? partial[t] : 0;
  s[t] = v;
  __syncthreads();
  for (int off = 1; off < 128; off <<= 1) {
    int add = (t >= off) ? s[t - off] : 0;
    __syncthreads();
    s[t] += add;
    __syncthreads();
  }
  int ex = (t == 0) ? 0 : s[t - 1];
  if (t < nb) partial[t] = ex;
}

// write row_start + cursor from chunk-local scan + chunk offset
__global__ __launch_bounds__(256) void k_scanwrite(const int* __restrict__ cnt,
                                                   const int* __restrict__ partial,
                                                   int* __restrict__ row_start,
                                                   int* __restrict__ cursor, int N) {
  __shared__ int s[256];
  int b = blockIdx.x, t = threadIdx.x;
  int base = b * 1024 + t * 4;
  int d[4];
  int sum = 0;
#pragma unroll
  for (int k = 0; k < 4; ++k) { int i = base + k; d[k] = (i < N) ? cnt[i] : 0; sum += d[k]; }
  s[t] = sum;
  __syncthreads();
  for (int off = 1; off < 256; off <<= 1) {
    int add = (t >= off) ? s[t - off] : 0;
    __syncthreads();
    s[t] += add;
    __syncthreads();
  }
  int ex = (t == 0) ? 0 : s[t - 1];
  int off0 = partial[b] + ex;
#pragma unroll
  for (int k = 0; k < 4; ++k) {
    int i = base + k;
    if (i < N) { row_start[i] = off0; cursor[i] = off0; off0 += d[k]; }
  }
}

__global__ void k_fill(const int* __restrict__ src, const int* __restrict__ dst,
                       int* __restrict__ cursor, int* __restrict__ csr, int E) {
  int i = blockIdx.x * blockDim.x + threadIdx.x;
  int stride = gridDim.x * blockDim.x;
  for (int e = i; e < E; e += stride) {
    int d = dst[e];
    int pos = atomicAdd(&cursor[d], 1);
    csr[pos] = src[e];
  }
}

// ============ gather-mean aggregation (no atomics) ============
// one wave per node, lane = channel (64ch)
__global__ __launch_bounds__(256) void k_gather1(const float* __restrict__ x,
                                                 const int* __restrict__ csr,
                                                 const int* __restrict__ row_start,
                                                 const int* __restrict__ cnt,
                                                 float* __restrict__ agg, int N) {
  int wid = (blockIdx.x * blockDim.x + threadIdx.x) >> 6;
  int lane = threadIdx.x & 63;
  if (wid >= N) return;
  int start = row_start[wid];
  int c = cnt[wid];
  int j = start, end = start + c;
  float v = 0.f;
  for (; j + 3 < end; j += 4) {
    int s0 = csr[j], s1 = csr[j + 1], s2 = csr[j + 2], s3 = csr[j + 3];
    float a0 = x[s0 * IN_C + lane];
    float a1 = x[s1 * IN_C + lane];
    float a2 = x[s2 * IN_C + lane];
    float a3 = x[s3 * IN_C + lane];
    v += a0 + a1 + a2 + a3;
  }
  for (; j < end; ++j) v += x[csr[j] * IN_C + lane];
  float inv = 1.0f / fmaxf((float)c, 1.0f);
  agg[wid * IN_C + lane] = v * inv;
}

// one wave per node, lane holds float2 (128ch)
__global__ __launch_bounds__(256) void k_gather2(const float* __restrict__ h,
                                                 const int* __restrict__ csr,
                                                 const int* __restrict__ row_start,
                                                 const int* __restrict__ cnt,
                                                 float* __restrict__ agg, int N) {
  int wid = (blockIdx.x * blockDim.x + threadIdx.x) >> 6;
  int lane = threadIdx.x & 63;
  if (wid >= N) return;
  const float2* h2 = (const float2*)h;
  int start = row_start[wid];
  int c = cnt[wid];
  int j = start, end = start + c;
  float vx = 0.f, vy = 0.f;
  for (; j + 1 < end; j += 2) {
    int s0 = csr[j], s1 = csr[j + 1];
    float2 a = h2[s0 * 64 + lane];
    float2 b = h2[s1 * 64 + lane];
    vx += a.x + b.x;
    vy += a.y + b.y;
  }
  if (j < end) {
    float2 a = h2[csr[j] * 64 + lane];
    vx += a.x;
    vy += a.y;
  }
  float inv = 1.0f / fmaxf((float)c, 1.0f);
  float2 r = {vx * inv, vy * inv};
  ((float2*)agg)[wid * 64 + lane] = r;
}

// -------- layer 1 linear: h = relu(agg @ W1l^T + x @ W1r^T + b1) --------
__global__ __launch_bounds__(256) void k_linear1(
    const float* __restrict__ agg, const float* __restrict__ x,
    const float* __restrict__ Wl, const float* __restrict__ Wr,
    const float* __restrict__ b, float* __restrict__ h, int N) {
  constexpr int NPB = 16;
  constexpr int WROW = 68;
  __shared__ __align__(16) float sWl[HID_C * WROW];
  __shared__ __align__(16) float sWr[HID_C * WROW];
  __shared__ float sb[HID_C];
  __shared__ __align__(16) float sfa[NPB][IN_C];
  __shared__ __align__(16) float sfx[NPB][IN_C];
  int t = threadIdx.x;
  for (int idx = t; idx < HID_C * IN_C; idx += 256) {
    int o = idx >> 6, c = idx & 63;
    sWl[o * WROW + c] = Wl[idx];
    sWr[o * WROW + c] = Wr[idx];
  }
  if (t < HID_C) sb[t] = b[t];
  int base = blockIdx.x * NPB;
  for (int idx = t; idx < NPB * IN_C; idx += 256) {
    int n = idx >> 6, c = idx & 63;
    int i = base + n;
    float a = 0.f, xv = 0.f;
    if (i < N) {
      a = agg[i * IN_C + c];
      xv = x[i * IN_C + c];
    }
    sfa[n][c] = a;
    sfx[n][c] = xv;
  }
  __syncthreads();
  int o = t & 127;
  int half = t >> 7;
  float4 wl[16], wr[16];
  const float4* pl = (const float4*)(sWl + o * WROW);
  const float4* pr = (const float4*)(sWr + o * WROW);
#pragma unroll
  for (int k = 0; k < 16; ++k) { wl[k] = pl[k]; wr[k] = pr[k]; }
  float bo = sb[o];
  for (int n = half; n < NPB; n += 2) {
    int i = base + n;
    if (i >= N) break;
    const float4* fa = (const float4*)(&sfa[n][0]);
    const float4* fx = (const float4*)(&sfx[n][0]);
    float acc = bo;
#pragma unroll
    for (int k = 0; k < 16; ++k) {
      float4 a4 = fa[k], x4 = fx[k];
      acc = fmaf(a4.x, wl[k].x, acc);
      acc = fmaf(a4.y, wl[k].y, acc);
      acc = fmaf(a4.z, wl[k].z, acc);
      acc = fmaf(a4.w, wl[k].w, acc);
      acc = fmaf(x4.x, wr[k].x, acc);
      acc = fmaf(x4.y, wr[k].y, acc);
      acc = fmaf(x4.z, wr[k].z, acc);
      acc = fmaf(x4.w, wr[k].w, acc);
    }
    h[i * HID_C + o] = fmaxf(acc, 0.f);
  }
}

// -------- layer 2 linear: out = sigmoid(agg2 @ W2l^T + h @ W2r^T + b2) ----
__global__ __launch_bounds__(256) void k_linear2(
    const float* __restrict__ agg, const float* __restrict__ h,
    const float* __restrict__ Wl, const float* __restrict__ Wr,
    const float* __restrict__ b, float* __restrict__ out, int N) {
  constexpr int NPB = 8;
  constexpr int WROW = 132;
  __shared__ __align__(16) float sWl[OUT_C * WROW];
  __shared__ __align__(16) float sWr[OUT_C * WROW];
  __shared__ float sb[OUT_C];
  __shared__ __align__(16) float sfa[NPB][HID_C];
  __shared__ __align__(16) float sfh[NPB][HID_C];
  __shared__ float sacc[NPB][OUT_C];
  int t = threadIdx.x;
  for (int idx = t; idx < OUT_C * HID_C; idx += 256) {
    int o = idx >> 7, c = idx & 127;
    sWl[o * WROW + c] = Wl[idx];
    sWr[o * WROW + c] = Wr[idx];
  }
  if (t < OUT_C) sb[t] = b[t];
  int base = blockIdx.x * NPB;
  for (int idx = t; idx < NPB * HID_C; idx += 256) {
    int n = idx >> 7, c = idx & 127;
    int i = base + n;
    float a = 0.f, hv = 0.f;
    if (i < N) {
      a = agg[i * HID_C + c];
      hv = h[i * HID_C + c];
    }
    sfa[n][c] = a;
    sfh[n][c] = hv;
  }
  __syncthreads();
  int o = t & 63;
  int chalf = (t >> 6) & 1;
  int npar = t >> 7;
  float4 wl[16], wr[16];
  const float4* pl = (const float4*)(sWl + o * WROW + chalf * 64);
  const float4* pr = (const float4*)(sWr + o * WROW + chalf * 64);
#pragma unroll
  for (int k = 0; k < 16; ++k) { wl[k] = pl[k]; wr[k] = pr[k]; }
  float part[NPB / 2];
#pragma unroll
  for (int ni = 0; ni < NPB / 2; ++ni) {
    int n = npar + 2 * ni;
    const float4* fa = (const float4*)(&sfa[n][chalf * 64]);
    const float4* fh = (const float4*)(&sfh[n][chalf * 64]);
    float acc = 0.f;
#pragma unroll
    for (int k = 0; k < 16; ++k) {
      float4 a4 = fa[k], h4 = fh[k];
      acc = fmaf(a4.x, wl[k].x, acc);
      acc = fmaf(a4.y, wl[k].y, acc);
      acc = fmaf(a4.z, wl[k].z, acc);
      acc = fmaf(a4.w, wl[k].w, acc);
      acc = fmaf(h4.x, wr[k].x, acc);
      acc = fmaf(h4.y, wr[k].y, acc);
      acc = fmaf(h4.z, wr[k].z, acc);
      acc = fmaf(h4.w, wr[k].w, acc);
    }
    part[ni] = acc;
  }
  if (chalf == 0) {
#pragma unroll
    for (int ni = 0; ni < NPB / 2; ++ni) sacc[npar + 2 * ni][o] = part[ni];
  }
  __syncthreads();
  if (chalf == 1) {
#pragma unroll
    for (int ni = 0; ni < NPB / 2; ++ni) {
      int n = npar + 2 * ni;
      int i = base + n;
      if (i < N) {
        float v = sacc[n][o] + part[ni] + sb[o];
        out[i * OUT_C + o] = 1.0f / (1.0f + __expf(-v));
      }
    }
  }
}

extern "C" void kernel_launch(void* const* d_in, const int* in_sizes, int n_in,
                              void* d_out, int out_size, void* d_ws, size_t ws_size,
                              hipStream_t stream) {
  const float* x   = (const float*)d_in[0];
  const int*   ei  = (const int*)d_in[1];
  const float* W1l = (const float*)d_in[2];
  const float* W1r = (const float*)d_in[3];
  const float* b1  = (const float*)d_in[4];
  const float* W2l = (const float*)d_in[5];
  const float* W2r = (const float*)d_in[6];
  const float* b2  = (const float*)d_in[7];
  float* out = (float*)d_out;

  int N = in_sizes[0] / IN_C;
  int E = in_sizes[1] / 2;
  const int* src = ei;
  const int* dst = ei + E;

  // ws layout (ints then floats, 512B-aligned sections):
  // [cnt N][row_start N][cursor N][partial 128][csr E] [agg N*128 f][h N*128 f]
  char* ws = (char*)d_ws;
  size_t off = 0;
  auto alignup = [](size_t v) { return (v + 511) & ~(size_t)511; };
  int* cnt = (int*)(ws + off);       off = alignup(off + (size_t)N * 4);
  int* row_start = (int*)(ws + off); off = alignup(off + (size_t)N * 4);
  int* cursor = (int*)(ws + off);    off = alignup(off + (size_t)N * 4);
  int* partial = (int*)(ws + off);   off = alignup(off + 128 * 4);
  int* csr = (int*)(ws + off);       off = alignup(off + (size_t)E * 4);
  float* aggbuf = (float*)(ws + off); off = alignup(off + (size_t)N * HID_C * 4);
  float* hbuf = (float*)(ws + off);

  int NB = (N + 1023) / 1024;  // chunks for scan (<=128 supported)

  // CSR build
  hipMemsetAsync(cnt, 0, (size_t)N * 4, stream);
  k_hist<<<2048, 256, 0, stream>>>(dst, cnt, E);
  k_blocksum<<<NB, 256, 0, stream>>>(cnt, partial, N);
  k_scanpart<<<1, 128, 0, stream>>>(partial, NB);
  k_scanwrite<<<NB, 256, 0, stream>>>(cnt, partial, row_start, cursor, N);
  k_fill<<<2048, 256, 0, stream>>>(src, dst, cursor, csr, E);

  // layer 1
  k_gather1<<<(N + 3) / 4, 256, 0, stream>>>(x, csr, row_start, cnt, aggbuf, N);
  k_linear1<<<(N + 15) / 16, 256, 0, stream>>>(aggbuf, x, W1l, W1r, b1, hbuf, N);
  // layer 2
  k_gather2<<<(N + 3) / 4, 256, 0, stream>>>(hbuf, csr, row_start, cnt, aggbuf, N);
  k_linear2<<<(N + 7) / 8, 256, 0, stream>>>(aggbuf, hbuf, W2l, W2r, b2, out, N);
}